// Round 2
// baseline (2568.513 us; speedup 1.0000x reference)
//
#include <hip/hip_runtime.h>
#include <math.h>

#define KCODES 8192
#define DDIM   256
#define NTOT   16384
#define QT     32     // queries per block
#define KT     128    // codes per k-tile
#define DC     32     // d-chunk for emb staging
#define ZPAD   36     // zs leading-dim pad (16B-aligned float4, conflict-free)
#define EPAD   132    // es leading-dim pad (16B-aligned float4)

// ws layout (floats): [0] loss accum, [64 .. 64+8192) e2[k], [8256 .. 8256+16384) z2[n]

__global__ void e2_kernel(const float* __restrict__ emb, float* __restrict__ ws) {
    // one wave per codebook row; 256 threads = 4 rows per block
    int row  = blockIdx.x * 4 + (threadIdx.x >> 6);
    int lane = threadIdx.x & 63;
    if (blockIdx.x == 0 && threadIdx.x == 0) ws[0] = 0.0f;  // zero loss accumulator
    const float4* r = (const float4*)(emb + (size_t)row * DDIM);
    float4 v = r[lane];  // 64 lanes * 4 = 256 elements
    float s = v.x * v.x + v.y * v.y + v.z * v.z + v.w * v.w;
    #pragma unroll
    for (int off = 32; off > 0; off >>= 1) s += __shfl_down(s, off, 64);
    if (lane == 0) ws[64 + row] = s;
}

// z2[n] = ||z_n||^2: exact (fp64) sum of fp32 squares, rounded once to fp32.
// Within <=1 ulp of numpy's pairwise fp32 sum; a per-query grid-multiple offset
// shifts all d2[n][k] identically -> argmin invariant.
__global__ void z2_kernel(const float* __restrict__ z, float* __restrict__ z2out) {
    int n  = blockIdx.x * 256 + threadIdx.x;   // grid 64 x 256 = 16384
    int b  = n >> 10;
    int hw = n & 1023;
    const float* base = z + (size_t)b * DDIM * 1024 + hw;
    double acc = 0.0;
    #pragma unroll 8
    for (int d = 0; d < 256; ++d) {
        float v  = base[(size_t)d * 1024];     // lanes: consecutive hw -> coalesced
        float sq = __fmul_rn(v, v);            // match np's fl32(z*z)
        acc += (double)sq;
    }
    z2out[n] = (float)acc;
}

__launch_bounds__(256, 2)
__global__ void vq_main(const float* __restrict__ z, const float* __restrict__ emb,
                        const float* __restrict__ e2, const float* __restrict__ z2w,
                        float* __restrict__ loss_accum,
                        float* __restrict__ out0, float* __restrict__ out1) {
    __shared__ float zs[DDIM][ZPAD];   // 36,864 B  (z tile, [d][q])
    __shared__ float es[DC][EPAD];     // 16,896 B  (emb chunk, [d][k])
    __shared__ float redv[32][33];     //  4,224 B
    __shared__ int   redi[32][33];     //  4,224 B
    __shared__ int   bidx[QT];
    __shared__ float wsum[4];

    const int tid = threadIdx.x;
    const int nb  = blockIdx.x * QT;      // first query of this block
    const int b   = nb >> 10;             // batch index (1024 hw per batch)
    const int hw0 = nb & 1023;

    // ---- stage full z tile: 32 queries x 256 d  (coalesced 128B segments) ----
    {
        const int q = tid & 31;
        const int dbase = tid >> 5;       // 0..7
        #pragma unroll
        for (int it = 0; it < 32; ++it) {
            int d = dbase + it * 8;
            zs[d][q] = z[((size_t)(b * DDIM + d)) * 1024 + hw0 + q];
        }
    }

    const int ty = tid >> 5;   // 0..7  -> query group (4 q each)
    const int tx = tid & 31;   // 0..31 -> code group  (4 k each)

    float z2q[4];
    *(float4*)z2q = *(const float4*)&z2w[nb + ty * 4];

    float bestv[4];
    int   besti[4];
    #pragma unroll
    for (int i = 0; i < 4; ++i) { bestv[i] = INFINITY; besti[i] = 0; }

    for (int kt = 0; kt < KCODES; kt += KT) {
        float acc[4][4];
        #pragma unroll
        for (int i = 0; i < 4; ++i)
            #pragma unroll
            for (int j = 0; j < 4; ++j) acc[i][j] = 0.0f;

        for (int dc = 0; dc < DDIM; dc += DC) {
            __syncthreads();  // protect es (and first-iter zs) before overwrite/use
            // stage emb chunk: KT codes x DC d  (16 elems/thread, coalesced)
            #pragma unroll
            for (int it = 0; it < 16; ++it) {
                int gid = tid + it * 256;
                int k = gid >> 5;          // 0..127
                int d = gid & 31;          // 0..31
                es[d][k] = emb[(size_t)(kt + k) * DDIM + (dc + d)];
            }
            __syncthreads();

            #pragma unroll
            for (int dd = 0; dd < DC; ++dd) {
                const int d = dc + dd;
                float zv4[4], ev4[4];
                *(float4*)zv4 = *(const float4*)&zs[d][ty * 4];   // broadcast across tx
                *(float4*)ev4 = *(const float4*)&es[dd][tx * 4];  // float4 strided
                #pragma unroll
                for (int i = 0; i < 4; ++i)
                    #pragma unroll
                    for (int j = 0; j < 4; ++j)
                        acc[i][j] = fmaf(zv4[i], ev4[j], acc[i][j]);
            }
        }

        // d2 = fl(fl(z2 - fl(2*dot)) + e2): reproduce the reference fp32 rounding
        float e2a[4];
        *(float4*)e2a = *(const float4*)&e2[kt + tx * 4];
        #pragma unroll
        for (int i = 0; i < 4; ++i) {
            #pragma unroll
            for (int j = 0; j < 4; ++j) {
                float t = __fsub_rn(z2q[i], __fmul_rn(2.0f, acc[i][j]));
                float s = __fadd_rn(t, e2a[j]);
                int   k = kt + tx * 4 + j;
                if (s < bestv[i]) { bestv[i] = s; besti[i] = k; }  // ascending k -> first-index ties
            }
        }
    }

    // ---- cross-thread argmin reduce (per query, over the 32 tx groups) ----
    #pragma unroll
    for (int i = 0; i < 4; ++i) {
        int p = ty * 4 + i;           // query 0..31 within block
        redv[p][tx] = bestv[i];
        redi[p][tx] = besti[i];
    }
    __syncthreads();
    if (tid < 32) {
        float bv = redv[tid][0];
        int   bi = redi[tid][0];
        for (int t = 1; t < 32; ++t) {    // ascending tx == ascending k
            float v = redv[tid][t];
            int   ii = redi[tid][t];
            if (v < bv || (v == bv && ii < bi)) { bv = v; bi = ii; }
        }
        bidx[tid] = bi;
        out1[nb + tid] = (float)bi;       // indices output (as float)
    }
    __syncthreads();

    // ---- fused epilogue: quantized_st + commit-loss partial ----
    {
        const int q  = tid & 31;
        const int dg = tid >> 5;          // 0..7
        const int myidx = bidx[q];
        const float* erow = emb + (size_t)myidx * DDIM;
        float lsum = 0.0f;
        #pragma unroll
        for (int i = 0; i < 32; ++i) {
            int d = dg + 8 * i;
            float zv = zs[d][q];
            float qv = erow[d];
            out0[((size_t)(b * DDIM + d)) * 1024 + hw0 + q] = zv + (qv - zv);  // straight-through
            float e = zv - qv;
            lsum += e * e;
        }
        #pragma unroll
        for (int off = 32; off > 0; off >>= 1) lsum += __shfl_down(lsum, off, 64);
        if ((tid & 63) == 0) wsum[tid >> 6] = lsum;
        __syncthreads();
        if (tid == 0) atomicAdd(loss_accum, wsum[0] + wsum[1] + wsum[2] + wsum[3]);
    }
}

__global__ void loss_final(const float* __restrict__ loss_accum, float* __restrict__ out2) {
    out2[0] = loss_accum[0] * (1.0f / 4194304.0f);
}

extern "C" void kernel_launch(void* const* d_in, const int* in_sizes, int n_in,
                              void* d_out, int out_size, void* d_ws, size_t ws_size,
                              hipStream_t stream) {
    (void)in_sizes; (void)n_in; (void)out_size; (void)ws_size;
    const float* z   = (const float*)d_in[0];   // (16,256,32,32)
    const float* emb = (const float*)d_in[1];   // (8192,256)
    float* ws_f  = (float*)d_ws;
    float* loss  = ws_f;            // [0]
    float* e2    = ws_f + 64;       // [64 .. 64+8192)
    float* z2    = ws_f + 64 + KCODES;  // 16384 floats
    float* out0  = (float*)d_out;                    // quantized_st: 4,194,304
    float* out1  = out0 + (size_t)4194304;           // indices:      16,384
    float* out2  = out1 + (size_t)16384;             // commit_loss:  1

    e2_kernel<<<KCODES / 4, 256, 0, stream>>>(emb, ws_f);
    z2_kernel<<<NTOT / 256, 256, 0, stream>>>(z, z2);
    vq_main<<<NTOT / QT, 256, 0, stream>>>(z, emb, e2, z2, loss, out0, out1);
    loss_final<<<1, 1, 0, stream>>>(loss, out2);
}

// Round 3
// 328.756 us; speedup vs baseline: 7.8128x; 7.8128x over previous
//
#include <hip/hip_runtime.h>
#include <math.h>

typedef _Float16 f16;
typedef _Float16 f16x8 __attribute__((ext_vector_type(8)));
typedef float f32x4 __attribute__((ext_vector_type(4)));

#define KCODES 8192
#define DDIM   256
#define NTOT   16384
#define QT     64      // queries per block
#define NKT    32      // k-tiles of 256 codes
#define CHB    32768   // chunk image bytes: 2 planes * 256 codes * 32 d * 2B

#define F16_MIN_NORMAL 6.103515625e-05f

// ws layout: [0] loss | +256B e2[8192] f32 | +33024B z2[16384] f32 | +131072B emb-plane image (8 MB)

__device__ __forceinline__ void gload_lds16(const void* g, void* l) {
    __builtin_amdgcn_global_load_lds(
        (const __attribute__((address_space(1))) void*)g,
        (__attribute__((address_space(3))) void*)l, 16, 0, 0);
}

__global__ void e2_kernel(const float* __restrict__ emb, float* __restrict__ ws) {
    int row  = blockIdx.x * 4 + (threadIdx.x >> 6);
    int lane = threadIdx.x & 63;
    if (blockIdx.x == 0 && threadIdx.x == 0) ws[0] = 0.0f;  // zero loss accumulator
    const float4* r = (const float4*)(emb + (size_t)row * DDIM);
    float4 v = r[lane];
    float s = v.x * v.x + v.y * v.y + v.z * v.z + v.w * v.w;
    #pragma unroll
    for (int off = 32; off > 0; off >>= 1) s += __shfl_down(s, off, 64);
    if (lane == 0) ws[64 + row] = s;
}

// z2[n]: exact (fp64) sum of fp32 squares, rounded once -> matches round-2 (verified absmax 0)
__global__ void z2_kernel(const float* __restrict__ z, float* __restrict__ z2out) {
    int n  = blockIdx.x * 256 + threadIdx.x;
    int b  = n >> 10;
    int hw = n & 1023;
    const float* base = z + (size_t)b * DDIM * 1024 + hw;
    double acc = 0.0;
    #pragma unroll 8
    for (int d = 0; d < 256; ++d) {
        float v  = base[(size_t)d * 1024];
        float sq = __fmul_rn(v, v);
        acc += (double)sq;
    }
    z2out[n] = (float)acc;
}

// split emb into 2 fp16 planes (pre-scaled by 2^13), stored as the exact swizzled LDS image
__global__ void esplit_kernel(const float* __restrict__ emb, char* __restrict__ img) {
    int c = blockIdx.x, d = threadIdx.x;
    float e = emb[(size_t)c * 256 + d] * 8192.0f;   // exact pow2 scale
    float eh = 0.0f;
    if (fabsf(e) >= F16_MIN_NORMAL) eh = (float)(f16)e;   // normal-or-zero hi plane
    f16 ehh = (f16)eh;
    f16 emm = (f16)((e - eh) * 2048.0f);                  // residual scaled 2^11 (normal-or-negligible)
    int kt = c >> 8, ch = d >> 5, ci = c & 255, dp = d & 31;
    char* p = img + (size_t)(kt * 8 + ch) * CHB;
    int off = (ci * 64 + dp * 2) ^ ((ci & 7) << 4);       // XOR swizzle (bits 4-6 only)
    *(f16*)(p + off) = ehh;
    *(f16*)(p + 16384 + off) = emm;
}

__launch_bounds__(512, 2)
__global__ void vq_main(const float* __restrict__ z, const float* __restrict__ emb,
                        const float* __restrict__ e2w, const float* __restrict__ z2w,
                        const char* __restrict__ img, float* __restrict__ loss_accum,
                        float* __restrict__ out0, float* __restrict__ out1) {
    __shared__ __align__(16) char es[2][CHB];   // 64 KB emb chunk double-buffer
    __shared__ __align__(16) char zsH[32768];   // z hi plane  [64 q][256 d] f16, swizzled
    __shared__ __align__(16) char zsM[32768];   // z mid plane (scaled 2^11)
    __shared__ float redv[8][QT];
    __shared__ int   redi[8][QT];
    __shared__ int   bidx[QT];
    __shared__ float wsum[8];

    const int tid  = threadIdx.x;
    const int w    = tid >> 6;     // wave 0..7 -> 32-code strip within each 256-code tile
    const int lane = tid & 63;
    const int l15  = lane & 15;
    const int lg   = lane >> 4;    // 0..3
    const int nb   = blockIdx.x * QT;
    const int b    = nb >> 10;
    const int hw0  = nb & 1023;

    // ---- build z fp16 planes in LDS (one-time) ----
    {
        const int q = tid & 63, dg = tid >> 6;
        #pragma unroll
        for (int i = 0; i < 32; ++i) {
            const int d = dg + i * 8;
            float zv = z[(size_t)(b * 256 + d) * 1024 + hw0 + q];
            float zh = 0.0f;
            if (fabsf(zv) >= F16_MIN_NORMAL) zh = (float)(f16)zv;
            const int off = (q * 512 + d * 2) ^ ((q & 7) << 4);
            *(f16*)(zsH + off) = (f16)zh;
            *(f16*)(zsM + off) = (f16)((zv - zh) * 2048.0f);
        }
    }

    // z2 for this lane's 16 query slots (C-layout rows)
    float z2r[4][4];
    #pragma unroll
    for (int m = 0; m < 4; ++m)
        #pragma unroll
        for (int r = 0; r < 4; ++r)
            z2r[m][r] = z2w[nb + m * 16 + lg * 4 + r];

    float bestv[4][4];
    int   besti[4][4];
    #pragma unroll
    for (int m = 0; m < 4; ++m)
        #pragma unroll
        for (int r = 0; r < 4; ++r) { bestv[m][r] = INFINITY; besti[m][r] = 0; }

    // prologue: stage chunk 0 into es[0]
    {
        const char* gsrc = img + (size_t)(w * 4) * 1024 + lane * 16;
        char* ldst = &es[0][(w * 4) * 1024];
        #pragma unroll
        for (int i = 0; i < 4; ++i) gload_lds16(gsrc + i * 1024, ldst + i * 1024);
    }
    __syncthreads();   // covers z-plane writes + stage-0

    for (int kt = 0; kt < NKT; ++kt) {
        f32x4 a1[4][2], a2[4][2], a3[4][2];
        const f32x4 vz = {0.0f, 0.0f, 0.0f, 0.0f};
        #pragma unroll
        for (int m = 0; m < 4; ++m)
            #pragma unroll
            for (int n = 0; n < 2; ++n) { a1[m][n] = vz; a2[m][n] = vz; a3[m][n] = vz; }
        float e2v[2];
        #pragma unroll
        for (int n = 0; n < 2; ++n)
            e2v[n] = e2w[kt * 256 + w * 32 + n * 16 + l15];

        #pragma unroll
        for (int ch = 0; ch < 8; ++ch) {
            const int t = kt * 8 + ch;
            if (t < NKT * 8 - 1) {   // stage next chunk into the other buffer
                const char* gsrc = img + (size_t)(t + 1) * CHB + (w * 4) * 1024 + lane * 16;
                char* ldst = &es[(ch + 1) & 1][(w * 4) * 1024];
                #pragma unroll
                for (int i = 0; i < 4; ++i) gload_lds16(gsrc + i * 1024, ldst + i * 1024);
            }
            const char* esb = es[ch & 1];
            f16x8 ah[4], am[4];
            #pragma unroll
            for (int m = 0; m < 4; ++m) {
                const int q = m * 16 + l15;
                const int off = (q * 512 + (ch * 32 + lg * 8) * 2) ^ ((q & 7) << 4);
                ah[m] = *(const f16x8*)(zsH + off);
                am[m] = *(const f16x8*)(zsM + off);
            }
            f16x8 bh[2], bm[2];
            #pragma unroll
            for (int n = 0; n < 2; ++n) {
                const int c = w * 32 + n * 16 + l15;
                const int off = (c * 64 + lg * 16) ^ ((c & 7) << 4);
                bh[n] = *(const f16x8*)(esb + off);
                bm[n] = *(const f16x8*)(esb + 16384 + off);
            }
            #pragma unroll
            for (int m = 0; m < 4; ++m)
                #pragma unroll
                for (int n = 0; n < 2; ++n) {
                    a1[m][n] = __builtin_amdgcn_mfma_f32_16x16x32_f16(ah[m], bh[n], a1[m][n], 0, 0, 0);
                    a2[m][n] = __builtin_amdgcn_mfma_f32_16x16x32_f16(ah[m], bm[n], a2[m][n], 0, 0, 0);
                    a2[m][n] = __builtin_amdgcn_mfma_f32_16x16x32_f16(am[m], bh[n], a2[m][n], 0, 0, 0);
                    a3[m][n] = __builtin_amdgcn_mfma_f32_16x16x32_f16(am[m], bm[n], a3[m][n], 0, 0, 0);
                }
            __syncthreads();   // drains stage (vmcnt) + LDS reads; next buffer ready
        }

        // ---- per-k-tile score + argmin (replicates ref fp32 rounding exactly) ----
        #pragma unroll
        for (int m = 0; m < 4; ++m)
            #pragma unroll
            for (int n = 0; n < 2; ++n) {
                const int code = kt * 256 + w * 32 + n * 16 + l15;
                #pragma unroll
                for (int r = 0; r < 4; ++r) {
                    float rr = fmaf(a3[m][n][r], 0x1p-11f, a2[m][n][r]);
                    rr = fmaf(rr, 0x1p-11f, a1[m][n][r]);           // dot * 2^13
                    float tt = fmaf(rr, -0x1p-12f, z2r[m][r]);      // = fl(z2 - 2*dot), single round
                    float s  = __fadd_rn(tt, e2v[n]);
                    if (s < bestv[m][r]) { bestv[m][r] = s; besti[m][r] = code; }  // ascending code -> first-index ties
                }
            }
    }

    // ---- cross-lane argmin within each 16-lane column group ----
    #pragma unroll
    for (int m = 0; m < 4; ++m)
        #pragma unroll
        for (int r = 0; r < 4; ++r) {
            float v = bestv[m][r]; int idx = besti[m][r];
            #pragma unroll
            for (int dlt = 1; dlt < 16; dlt <<= 1) {
                float v2 = __shfl_xor(v, dlt, 64);
                int   i2 = __shfl_xor(idx, dlt, 64);
                if (v2 < v || (v2 == v && i2 < idx)) { v = v2; idx = i2; }
            }
            if (l15 == 0) {
                const int q = m * 16 + lg * 4 + r;
                redv[w][q] = v; redi[w][q] = idx;
            }
        }
    __syncthreads();
    if (tid < QT) {
        float bv = redv[0][tid]; int bi = redi[0][tid];
        #pragma unroll
        for (int ww = 1; ww < 8; ++ww) {
            float v = redv[ww][tid]; int ii = redi[ww][tid];
            if (v < bv || (v == bv && ii < bi)) { bv = v; bi = ii; }
        }
        bidx[tid] = bi;
        out1[nb + tid] = (float)bi;
    }
    __syncthreads();

    // ---- fused epilogue: quantized_st + commit-loss partial (fp32, round-2 verified) ----
    {
        const int q = tid & 63, dg = tid >> 6;
        const int myidx = bidx[q];
        const float* erow = emb + (size_t)myidx * 256;
        float lsum = 0.0f;
        #pragma unroll
        for (int i = 0; i < 32; ++i) {
            const int d = dg + 8 * i;
            const size_t gi = (size_t)(b * 256 + d) * 1024 + hw0 + q;
            float zv = z[gi];
            float qv = erow[d];
            out0[gi] = zv + (qv - zv);
            float e = zv - qv;
            lsum += e * e;
        }
        #pragma unroll
        for (int off = 32; off > 0; off >>= 1) lsum += __shfl_down(lsum, off, 64);
        if (lane == 0) wsum[w] = lsum;
        __syncthreads();
        if (tid == 0) {
            float s = 0.0f;
            #pragma unroll
            for (int i = 0; i < 8; ++i) s += wsum[i];
            atomicAdd(loss_accum, s);
        }
    }
}

__global__ void loss_final(const float* __restrict__ loss_accum, float* __restrict__ out2) {
    out2[0] = loss_accum[0] * (1.0f / 4194304.0f);
}

extern "C" void kernel_launch(void* const* d_in, const int* in_sizes, int n_in,
                              void* d_out, int out_size, void* d_ws, size_t ws_size,
                              hipStream_t stream) {
    (void)in_sizes; (void)n_in; (void)out_size; (void)ws_size;
    const float* z   = (const float*)d_in[0];   // (16,256,32,32)
    const float* emb = (const float*)d_in[1];   // (8192,256)
    float* ws_f = (float*)d_ws;
    char*  wsb  = (char*)d_ws;
    float* loss = ws_f;                          // [0]
    float* e2   = ws_f + 64;                     // 8192 f32
    float* z2   = ws_f + 64 + KCODES;            // 16384 f32
    char*  img  = wsb + 131072;                  // 8 MB fp16-plane image
    float* out0 = (float*)d_out;                 // quantized_st: 4,194,304
    float* out1 = out0 + (size_t)4194304;        // indices:      16,384
    float* out2 = out1 + (size_t)16384;          // commit_loss:  1

    e2_kernel<<<KCODES / 4, 256, 0, stream>>>(emb, ws_f);
    z2_kernel<<<NTOT / 256, 256, 0, stream>>>(z, z2);
    esplit_kernel<<<KCODES, 256, 0, stream>>>(emb, img);
    vq_main<<<NTOT / QT, 512, 0, stream>>>(z, emb, e2, z2, img, loss, out0, out1);
    loss_final<<<1, 1, 0, stream>>>(loss, out2);
}

// Round 4
// 316.537 us; speedup vs baseline: 8.1144x; 1.0386x over previous
//
#include <hip/hip_runtime.h>
#include <math.h>

typedef _Float16 f16;
typedef _Float16 f16x8 __attribute__((ext_vector_type(8)));
typedef float f32x4 __attribute__((ext_vector_type(4)));

#define KCODES 8192
#define DDIM   256
#define NTOT   16384
#define QT     64      // queries per block
#define NKT    32      // k-tiles of 256 codes
#define NCH    256     // total 32KB chunks = NKT*8
#define CHB    32768   // chunk image bytes: 2 planes * 256 codes * 32 d * 2B

#define F16_MIN_NORMAL 6.103515625e-05f
#define MEMFENCE asm volatile("" ::: "memory")

// ws layout: [0] loss | +256B e2[8192] f32 | z2[16384] f32 | +131072B emb-plane image (8 MB)

__device__ __forceinline__ void gload_lds16(const void* g, void* l) {
    __builtin_amdgcn_global_load_lds(
        (const __attribute__((address_space(1))) void*)g,
        (__attribute__((address_space(3))) void*)l, 16, 0, 0);
}

// z2[n]: exact (fp64) sum of fp32 squares, rounded once (round-2/3 verified). Also zeroes loss.
__global__ void z2_kernel(const float* __restrict__ z, float* __restrict__ z2out,
                          float* __restrict__ loss) {
    int n  = blockIdx.x * 256 + threadIdx.x;
    if (n == 0) loss[0] = 0.0f;
    int b  = n >> 10;
    int hw = n & 1023;
    const float* base = z + (size_t)b * DDIM * 1024 + hw;
    double acc = 0.0;
    #pragma unroll 8
    for (int d = 0; d < 256; ++d) {
        float v  = base[(size_t)d * 1024];
        float sq = __fmul_rn(v, v);
        acc += (double)sq;
    }
    z2out[n] = (float)acc;
}

// split emb into 2 fp16 planes (pre-scaled by 2^13) as the swizzled LDS image; fused e2.
__global__ void esplit_kernel(const float* __restrict__ emb, char* __restrict__ img,
                              float* __restrict__ e2out) {
    __shared__ double part[4];
    int c = blockIdx.x, d = threadIdx.x;
    float ev = emb[(size_t)c * 256 + d];
    // e2 (any accurate fp32 value works: enters ~1e-13 below the error budget)
    double sq = (double)__fmul_rn(ev, ev);
    #pragma unroll
    for (int off = 32; off > 0; off >>= 1) sq += __shfl_down(sq, off, 64);
    if ((d & 63) == 0) part[d >> 6] = sq;
    __syncthreads();
    if (d == 0) e2out[c] = (float)(part[0] + part[1] + part[2] + part[3]);
    // plane split (bit-identical to round 3)
    float e = ev * 8192.0f;                               // exact pow2 scale
    float eh = 0.0f;
    if (fabsf(e) >= F16_MIN_NORMAL) eh = (float)(f16)e;   // normal-or-zero hi plane
    f16 ehh = (f16)eh;
    f16 emm = (f16)((e - eh) * 2048.0f);                  // residual scaled 2^11
    int kt = c >> 8, ch = d >> 5, ci = c & 255, dp = d & 31;
    char* p = img + (size_t)(kt * 8 + ch) * CHB;
    int off2 = (ci * 64 + dp * 2) ^ ((ci & 7) << 4);      // XOR swizzle (bits 4-6)
    *(f16*)(p + off2) = ehh;
    *(f16*)(p + 16384 + off2) = emm;
}

__launch_bounds__(512, 2)
__global__ void vq_main(const float* __restrict__ z, const float* __restrict__ emb,
                        const float* __restrict__ e2w, const float* __restrict__ z2w,
                        const char* __restrict__ img, float* __restrict__ loss_accum,
                        float* __restrict__ out0, float* __restrict__ out1) {
    __shared__ __align__(16) char es[2][CHB];     // 64 KB emb chunk double-buffer
    __shared__ __align__(16) char zsH[32768];     // z hi plane  [64 q][256 d] f16, swizzled
    __shared__ __align__(16) char zsM[32768];     // z mid plane (scaled 2^11)
    __shared__ __align__(16) float e2s[2][256];   // e2 double-buffer (staged per k-tile)
    __shared__ float redv[8][QT];
    __shared__ int   redi[8][QT];
    __shared__ int   bidx[QT];
    __shared__ float wsum[8];

    const int tid  = threadIdx.x;
    const int w    = tid >> 6;
    const int lane = tid & 63;
    const int l15  = lane & 15;
    const int lg   = lane >> 4;
    const int nb   = blockIdx.x * QT;
    const int b    = nb >> 10;
    const int hw0  = nb & 1023;

    // prologue: issue stage of chunk 0 (latency hides under z-build)
    {
        const char* gsrc = img + (size_t)(w * 4) * 1024 + lane * 16;
        char* ldst = &es[0][(w * 4) * 1024];
        #pragma unroll
        for (int i = 0; i < 4; ++i) gload_lds16(gsrc + i * 1024, ldst + i * 1024);
    }

    // ---- build z fp16 planes in LDS (bit-identical to round 3) ----
    {
        const int q = tid & 63, dg = tid >> 6;
        #pragma unroll
        for (int i = 0; i < 32; ++i) {
            const int d = dg + i * 8;
            float zv = z[(size_t)(b * 256 + d) * 1024 + hw0 + q];
            float zh = 0.0f;
            if (fabsf(zv) >= F16_MIN_NORMAL) zh = (float)(f16)zv;
            const int off = (q * 512 + d * 2) ^ ((q & 7) << 4);
            *(f16*)(zsH + off) = (f16)zh;
            *(f16*)(zsM + off) = (f16)((zv - zh) * 2048.0f);
        }
    }

    float z2r[4][4];
    #pragma unroll
    for (int m = 0; m < 4; ++m)
        #pragma unroll
        for (int r = 0; r < 4; ++r)
            z2r[m][r] = z2w[nb + m * 16 + lg * 4 + r];

    float bestv[4][4];
    int   besti[4][4];
    #pragma unroll
    for (int m = 0; m < 4; ++m)
        #pragma unroll
        for (int r = 0; r < 4; ++r) { bestv[m][r] = INFINITY; besti[m][r] = 0; }

    __syncthreads();   // one full drain: z planes + stage-0 complete + all waves aligned

    for (int kt = 0; kt < NKT; ++kt) {
        f32x4 a1[4][2], a2[4][2], a3[4][2];
        const f32x4 vz = {0.0f, 0.0f, 0.0f, 0.0f};
        #pragma unroll
        for (int m = 0; m < 4; ++m)
            #pragma unroll
            for (int n = 0; n < 2; ++n) { a1[m][n] = vz; a2[m][n] = vz; a3[m][n] = vz; }

        #pragma unroll
        for (int ch = 0; ch < 8; ++ch) {
            const int t = kt * 8 + ch;
            // [A] issue next-chunk stage (4 gload_lds) — stays in flight across barriers
            if (t < NCH - 1) {
                const char* gsrc = img + (size_t)(t + 1) * CHB + (size_t)(w * 4) * 1024 + lane * 16;
                char* ldst = &es[(ch + 1) & 1][(w * 4) * 1024];
                #pragma unroll
                for (int i = 0; i < 4; ++i) gload_lds16(gsrc + i * 1024, ldst + i * 1024);
            }
            if (ch == 0) {
                // e2 for this k-tile: 1 KB, all 8 waves stage identical copy (uniform vmcnt)
                gload_lds16((const char*)e2w + (size_t)kt * 1024 + lane * 16,
                            (char*)&e2s[kt & 1][0]);
            }
            // [B] counted vmcnt: wait own stage(t), keep stage(t+1)(+e2) in flight
            if (ch == 7 && kt == NKT - 1) asm volatile("s_waitcnt vmcnt(0)" ::: "memory");
            else if (ch == 0)             asm volatile("s_waitcnt vmcnt(5)" ::: "memory");
            else                          asm volatile("s_waitcnt vmcnt(4)" ::: "memory");
            // [C] publish buf[t&1] across waves
            __builtin_amdgcn_s_barrier();
            MEMFENCE;
            // [D] fragment reads from buf[ch&1]
            const char* esb = es[ch & 1];
            f16x8 ah[4], am[4];
            #pragma unroll
            for (int m = 0; m < 4; ++m) {
                const int q = m * 16 + l15;
                const int off = (q * 512 + (ch * 32 + lg * 8) * 2) ^ ((q & 7) << 4);
                ah[m] = *(const f16x8*)(zsH + off);
                am[m] = *(const f16x8*)(zsM + off);
            }
            f16x8 bh[2], bm[2];
            #pragma unroll
            for (int n = 0; n < 2; ++n) {
                const int c = w * 32 + n * 16 + l15;
                const int off = (c * 64 + lg * 16) ^ ((c & 7) << 4);
                bh[n] = *(const f16x8*)(esb + off);
                bm[n] = *(const f16x8*)(esb + 16384 + off);
            }
            // [E] MFMA cluster (bit-identical accumulation to round 3)
            __builtin_amdgcn_s_setprio(1);
            #pragma unroll
            for (int m = 0; m < 4; ++m)
                #pragma unroll
                for (int n = 0; n < 2; ++n) {
                    a1[m][n] = __builtin_amdgcn_mfma_f32_16x16x32_f16(ah[m], bh[n], a1[m][n], 0, 0, 0);
                    a2[m][n] = __builtin_amdgcn_mfma_f32_16x16x32_f16(ah[m], bm[n], a2[m][n], 0, 0, 0);
                    a2[m][n] = __builtin_amdgcn_mfma_f32_16x16x32_f16(am[m], bh[n], a2[m][n], 0, 0, 0);
                    a3[m][n] = __builtin_amdgcn_mfma_f32_16x16x32_f16(am[m], bm[n], a3[m][n], 0, 0, 0);
                }
            __builtin_amdgcn_s_setprio(0);
            // [F] all waves done reading buf[t&1] -> next iter may stage over other buf
            MEMFENCE;
            __builtin_amdgcn_s_barrier();
            MEMFENCE;
        }

        // ---- per-k-tile score + argmin (replicates ref fp32 rounding exactly) ----
        float e2v[2];
        #pragma unroll
        for (int n = 0; n < 2; ++n)
            e2v[n] = e2s[kt & 1][w * 32 + n * 16 + l15];
        #pragma unroll
        for (int m = 0; m < 4; ++m)
            #pragma unroll
            for (int n = 0; n < 2; ++n) {
                const int code = kt * 256 + w * 32 + n * 16 + l15;
                #pragma unroll
                for (int r = 0; r < 4; ++r) {
                    float rr = fmaf(a3[m][n][r], 0x1p-11f, a2[m][n][r]);
                    rr = fmaf(rr, 0x1p-11f, a1[m][n][r]);           // dot * 2^13
                    float tt = fmaf(rr, -0x1p-12f, z2r[m][r]);      // = fl(z2 - 2*dot), single round
                    float s  = __fadd_rn(tt, e2v[n]);
                    if (s < bestv[m][r]) { bestv[m][r] = s; besti[m][r] = code; }
                }
            }
    }

    // ---- cross-lane argmin within each 16-lane column group ----
    #pragma unroll
    for (int m = 0; m < 4; ++m)
        #pragma unroll
        for (int r = 0; r < 4; ++r) {
            float v = bestv[m][r]; int idx = besti[m][r];
            #pragma unroll
            for (int dlt = 1; dlt < 16; dlt <<= 1) {
                float v2 = __shfl_xor(v, dlt, 64);
                int   i2 = __shfl_xor(idx, dlt, 64);
                if (v2 < v || (v2 == v && i2 < idx)) { v = v2; idx = i2; }
            }
            if (l15 == 0) {
                const int q = m * 16 + lg * 4 + r;
                redv[w][q] = v; redi[w][q] = idx;
            }
        }
    __syncthreads();
    if (tid < QT) {
        float bv = redv[0][tid]; int bi = redi[0][tid];
        #pragma unroll
        for (int ww = 1; ww < 8; ++ww) {
            float v = redv[ww][tid]; int ii = redi[ww][tid];
            if (v < bv || (v == bv && ii < bi)) { bv = v; bi = ii; }
        }
        bidx[tid] = bi;
        out1[nb + tid] = (float)bi;
    }
    __syncthreads();

    // ---- fused epilogue: quantized_st + commit-loss partial (round-2/3 verified) ----
    {
        const int q = tid & 63, dg = tid >> 6;
        const int myidx = bidx[q];
        const float* erow = emb + (size_t)myidx * 256;
        float lsum = 0.0f;
        #pragma unroll
        for (int i = 0; i < 32; ++i) {
            const int d = dg + 8 * i;
            const size_t gi = (size_t)(b * 256 + d) * 1024 + hw0 + q;
            float zv = z[gi];
            float qv = erow[d];
            out0[gi] = zv + (qv - zv);
            float e = zv - qv;
            lsum += e * e;
        }
        #pragma unroll
        for (int off = 32; off > 0; off >>= 1) lsum += __shfl_down(lsum, off, 64);
        if (lane == 0) wsum[w] = lsum;
        __syncthreads();
        if (tid == 0) {
            float s = 0.0f;
            #pragma unroll
            for (int i = 0; i < 8; ++i) s += wsum[i];
            atomicAdd(loss_accum, s);
        }
    }
}

__global__ void loss_final(const float* __restrict__ loss_accum, float* __restrict__ out2) {
    out2[0] = loss_accum[0] * (1.0f / 4194304.0f);
}

extern "C" void kernel_launch(void* const* d_in, const int* in_sizes, int n_in,
                              void* d_out, int out_size, void* d_ws, size_t ws_size,
                              hipStream_t stream) {
    (void)in_sizes; (void)n_in; (void)out_size; (void)ws_size;
    const float* z   = (const float*)d_in[0];   // (16,256,32,32)
    const float* emb = (const float*)d_in[1];   // (8192,256)
    float* ws_f = (float*)d_ws;
    char*  wsb  = (char*)d_ws;
    float* loss = ws_f;                          // [0]
    float* e2   = ws_f + 64;                     // 8192 f32 (16B-aligned for gload_lds)
    float* z2   = ws_f + 64 + KCODES;            // 16384 f32
    char*  img  = wsb + 131072;                  // 8 MB fp16-plane image
    float* out0 = (float*)d_out;                 // quantized_st: 4,194,304
    float* out1 = out0 + (size_t)4194304;        // indices:      16,384
    float* out2 = out1 + (size_t)16384;          // commit_loss:  1

    esplit_kernel<<<KCODES, 256, 0, stream>>>(emb, img, e2);
    z2_kernel<<<NTOT / 256, 256, 0, stream>>>(z, z2, loss);
    vq_main<<<NTOT / QT, 512, 0, stream>>>(z, emb, e2, z2, img, loss, out0, out1);
    loss_final<<<1, 1, 0, stream>>>(loss, out2);
}